// Round 7
// baseline (140.524 us; speedup 1.0000x reference)
//
#include <hip/hip_runtime.h>
#include <stdint.h>

// DenseAttention_61598420959334 — round 7:
//   Identical to round 6 EXCEPT: k_gram's kt loop is NOT unrolled
//   (#pragma unroll 1). r5/r6 showed k_gram flat at ~76us regardless of
//   occupancy with all pipes idle => hypothesis: fully-unrolled ~60KB loop
//   body thrashes the per-CU instruction cache; fetch BW is the shared
//   saturated resource. Rolled body ~5KB fits I$.

#define DD 128
#define ROWS_PER_BLK 512
#define KSTEPS 16
#define PART_STRIDE 16512  // 16384 G-partial + 128 s-partial

typedef float f32x4 __attribute__((ext_vector_type(4)));
typedef short s16x8 __attribute__((ext_vector_type(8)));
typedef float fvec4 __attribute__((ext_vector_type(4)));

__device__ __forceinline__ unsigned short f2bf(float f) {
    union { float f; uint32_t u; } v; v.f = f;
    uint32_t u = v.u;
    u += 0x7FFFu + ((u >> 16) & 1u);
    return (unsigned short)(u >> 16);
}
__device__ __forceinline__ float bf2f(unsigned short h) {
    union { uint32_t u; float f; } v; v.u = ((uint32_t)h) << 16;
    return v.f;
}

// ---------------------------------------------------------------- pass 1: Gram
__global__ __launch_bounds__(512, 2) void k_gram(const float* __restrict__ x,
                                                 float* __restrict__ ws,
                                                 unsigned short* __restrict__ x16) {
    __shared__ short xs[2][2][4096];  // [buf][hi/lo][ j*128 + (d ^ ((j&7)<<3)) ]
    __shared__ short xt[2][2][4096];  // [buf][hi/lo][ a*32  + (j ^ (((a>>1)&3)<<3)) ]

    const int tid = threadIdx.x;
    const int l = tid & 63, w = tid >> 6;
    const int hi = l >> 4, c = l & 15;
    const int wr = w >> 1, wc = w & 1;
    const long rowbase = (long)blockIdx.x * ROWS_PER_BLK;
    const fvec4* xg = (const fvec4*)x;

    s16x8 ones;
#pragma unroll
    for (int i = 0; i < 8; ++i) ones[i] = (short)0x3F80;
    s16x8 idfw;  // identity B-frag for this wave's a-subtile
    {
        int tgt = (w & 1) * 16 + c - hi * 8;
#pragma unroll
        for (int i = 0; i < 8; ++i) idfw[i] = (i == tgt) ? (short)0x3F80 : (short)0;
    }

    f32x4 acc[2][4] = {};
    f32x4 accs = {};
    const f32x4 zero4 = {};

    fvec4 rA0, rA1, rB0, rB1;

#define LOADS(kt, r0, r1) do {                                  \
        long _b = (rowbase + (long)(kt) * 32) * 32;             \
        r0 = xg[_b + tid]; r1 = xg[_b + 512 + tid];             \
    } while (0)

#define CVTWRITE(BUF, r0, r1) do {                                              \
        _Pragma("unroll")                                                       \
        for (int _q = 0; _q < 2; ++_q) {                                        \
            fvec4 _v = _q ? r1 : r0;                                            \
            int _ft = tid + _q * 512;                                           \
            int _j = _ft >> 5, _d0 = (_ft & 31) * 4;                            \
            uint64_t _ph = 0, _pl = 0;                                          \
            _Pragma("unroll")                                                   \
            for (int _e = 0; _e < 4; ++_e) {                                    \
                float _f = _v[_e];                                              \
                unsigned short _hb = f2bf(_f);                                  \
                unsigned short _lb = f2bf(_f - bf2f(_hb));                      \
                _ph |= (uint64_t)_hb << (16 * _e);                              \
                _pl |= (uint64_t)_lb << (16 * _e);                              \
            }                                                                   \
            int _idx = _j * 128 + (_d0 ^ ((_j & 7) << 3));                      \
            *(uint64_t*)&xs[BUF][0][_idx] = _ph;                                \
            *(uint64_t*)&xs[BUF][1][_idx] = _pl;                                \
        }                                                                       \
    } while (0)

    // dump pre-swizzled bf16-hi tile to global (for k_out16)
#define DUMP(BUF, kt) do {                                                      \
        if (x16) {                                                              \
            long _o = (rowbase + (long)(kt) * 32) * 128 + tid * 8;              \
            *(s16x8*)&x16[_o] = *(const s16x8*)&xs[BUF][0][tid * 8];            \
        }                                                                       \
    } while (0)

#define XTBUILD(BUF) do {                                                       \
        const int _ks = w >> 1;                                                 \
        _Pragma("unroll")                                                       \
        for (int _jt = 0; _jt < 2; ++_jt) {                                     \
            int _j = _jt * 16 + c;                                              \
            int _rb = _j * 128 + ((_ks * 32 + hi * 8) ^ ((_j & 7) << 3));       \
            _Pragma("unroll")                                                   \
            for (int _hl = 0; _hl < 2; ++_hl) {                                 \
                s16x8 _af = *(const s16x8*)&xs[BUF][_hl][_rb];                  \
                f32x4 _d = __builtin_amdgcn_mfma_f32_16x16x32_bf16(_af, idfw, zero4, 0, 0, 0); \
                int _a = w * 16 + c;                                            \
                int _j0 = _jt * 16 + hi * 4;                                    \
                uint64_t _pk = 0;                                               \
                _Pragma("unroll")                                               \
                for (int _e = 0; _e < 4; ++_e) _pk |= (uint64_t)f2bf(_d[_e]) << (16 * _e); \
                *(uint64_t*)&xt[BUF][_hl][_a * 32 + (_j0 ^ (((_a >> 1) & 3) << 3))] = _pk; \
            }                                                                   \
        }                                                                       \
    } while (0)

#define GRAM(BUF) do {                                                          \
        s16x8 Ah[2], Al[2];                                                     \
        _Pragma("unroll")                                                       \
        for (int _mi = 0; _mi < 2; ++_mi) {                                     \
            int _a = (wr * 2 + _mi) * 16 + c;                                   \
            int _idx = _a * 32 + ((hi * 8) ^ (((_a >> 1) & 3) << 3));           \
            Ah[_mi] = *(const s16x8*)&xt[BUF][0][_idx];                         \
            Al[_mi] = *(const s16x8*)&xt[BUF][1][_idx];                         \
        }                                                                       \
        _Pragma("unroll")                                                       \
        for (int _ni = 0; _ni < 4; ++_ni) {                                     \
            int _b = (wc * 4 + _ni) * 16 + c;                                   \
            int _idx = _b * 32 + ((hi * 8) ^ (((_b >> 1) & 3) << 3));           \
            s16x8 Bh = *(const s16x8*)&xt[BUF][0][_idx];                        \
            s16x8 Bl = *(const s16x8*)&xt[BUF][1][_idx];                        \
            _Pragma("unroll")                                                   \
            for (int _mi = 0; _mi < 2; ++_mi) {                                 \
                acc[_mi][_ni] = __builtin_amdgcn_mfma_f32_16x16x32_bf16(Ah[_mi], Bh, acc[_mi][_ni], 0, 0, 0); \
                acc[_mi][_ni] = __builtin_amdgcn_mfma_f32_16x16x32_bf16(Ah[_mi], Bl, acc[_mi][_ni], 0, 0, 0); \
                acc[_mi][_ni] = __builtin_amdgcn_mfma_f32_16x16x32_bf16(Al[_mi], Bh, acc[_mi][_ni], 0, 0, 0); \
            }                                                                   \
            if (_ni == wr) {                                                    \
                accs = __builtin_amdgcn_mfma_f32_16x16x32_bf16(ones, Bh, accs, 0, 0, 0); \
                accs = __builtin_amdgcn_mfma_f32_16x16x32_bf16(ones, Bl, accs, 0, 0, 0); \
            }                                                                   \
        }                                                                       \
    } while (0)

    LOADS(0, rA0, rA1);
    CVTWRITE(0, rA0, rA1);
    LOADS(1, rB0, rB1);
    __syncthreads();

    // NOT unrolled: keep the hot-loop body ~5KB so it stays in I$ (r6 theory:
    // fully-unrolled ~60KB body thrashes per-CU instruction fetch).
#pragma unroll 1
    for (int kt = 0; kt < KSTEPS; kt += 2) {
        if (kt + 2 < KSTEPS) LOADS(kt + 2, rA0, rA1);
        XTBUILD(0);
        DUMP(0, kt);
        __syncthreads();
        GRAM(0);
        if (kt + 1 < KSTEPS) CVTWRITE(1, rB0, rB1);
        __syncthreads();

        if (kt + 3 < KSTEPS) LOADS(kt + 3, rB0, rB1);
        XTBUILD(1);
        DUMP(1, kt + 1);
        __syncthreads();
        GRAM(1);
        if (kt + 2 < KSTEPS) CVTWRITE(0, rA0, rA1);
        __syncthreads();
    }

    long pbase = (long)blockIdx.x * PART_STRIDE;
#pragma unroll
    for (int mi = 0; mi < 2; ++mi)
#pragma unroll
        for (int ni = 0; ni < 4; ++ni)
#pragma unroll
            for (int e = 0; e < 4; ++e) {
                int a = (wr * 2 + mi) * 16 + hi * 4 + e;
                int b = (wc * 4 + ni) * 16 + c;
                ws[pbase + a * 128 + b] = acc[mi][ni][e];
            }
    if (hi == 0) {
        int nbs = wc * 4 + wr;
        ws[pbase + 16384 + nbs * 16 + c] = accs[0];
    }
#undef LOADS
#undef CVTWRITE
#undef DUMP
#undef XTBUILD
#undef GRAM
}

// ------------------------------------------------------- reduce partials -> G, s
__global__ __launch_bounds__(256) void k_reduce(const float* __restrict__ parts,
                                                float* __restrict__ g_out,
                                                float* __restrict__ s_out, int nb1) {
    __shared__ float red[256];
    int b = blockIdx.x, t = threadIdx.x;
    if (b < 512) {
        int d1 = b >> 2, q = b & 3;
        int c32 = t & 31, pg = t >> 5;
        int per = nb1 >> 3;
        int e = d1 * 128 + q * 32 + c32;
        float acc = 0.f;
#pragma unroll 4
        for (int p = pg * per; p < (pg + 1) * per; ++p)
            acc += parts[(long)p * PART_STRIDE + e];
        red[t] = acc;
        __syncthreads();
        if (pg == 0) {
            float s = red[c32];
#pragma unroll
            for (int k = 1; k < 8; ++k) s += red[k * 32 + c32];
            g_out[e] = s;
        }
    } else {
        int ee = t & 127, hg = t >> 7;
        int per = nb1 >> 1;
        float acc = 0.f;
#pragma unroll 4
        for (int p = hg * per; p < (hg + 1) * per; ++p)
            acc += parts[(long)p * PART_STRIDE + 16384 + ee];
        red[t] = acc;
        __syncthreads();
        if (hg == 0) s_out[ee] = red[ee] + red[128 + ee];
    }
}

// ---- k_mid: scores row a from G (in LDS) + softmax + M row + c/wsum + casts
//      256 threads: two 64-wide segments split every 128-length dot.
__global__ __launch_bounds__(256) void k_mid(const float* __restrict__ G,
                                             const float* __restrict__ s,
                                             const float* __restrict__ Wq,
                                             const float* __restrict__ bq,
                                             const float* __restrict__ Wk,
                                             const float* __restrict__ bk,
                                             const float* __restrict__ Wv,
                                             const float* __restrict__ bv,
                                             const float* __restrict__ Wo,
                                             unsigned short* __restrict__ M16,
                                             unsigned short* __restrict__ Wo16,
                                             float* __restrict__ cvec,
                                             float* __restrict__ wsum, float Bn) {
    __shared__ float gl[16384];      // G row-major
    __shared__ float wk[128 * 129];  // Wk padded (conflict-free row reads)
    __shared__ float wqr[128], sl[128], bkl[128], bvl[128];
    __shared__ float prt[2][128], prt2[2][128];
    __shared__ float tmp[128], scl[128], wrow[128], scl2[128];
    int t = threadIdx.x, a = blockIdx.x;
    int tt = t & 127, seg = t >> 7;

    {
        const fvec4* gg = (const fvec4*)G;
        fvec4* gs = (fvec4*)gl;
        for (int i = t; i < 4096; i += 256) gs[i] = gg[i];
    }
    for (int idx = t; idx < 16384; idx += 256) {
        int r = idx >> 7, cc = idx & 127;
        wk[r * 129 + cc] = Wk[idx];
    }
    if (t < 128) {
        wqr[t] = Wq[a * 128 + t];
        sl[t] = s[t]; bkl[t] = bk[t]; bvl[t] = bv[t];
    }
    __syncthreads();

    // tmp[d2] = Wq[a,:] . G[:,d2]   split over 2 segments of 64
    float tm = 0.f;
#pragma unroll 8
    for (int d1 = seg * 64; d1 < seg * 64 + 64; ++d1) tm += wqr[d1] * gl[d1 * 128 + tt];
    prt[seg][tt] = tm;
    __syncthreads();
    if (t < 128) tmp[t] = prt[0][t] + prt[1][t];
    __syncthreads();

    // scores[a][t]
    float p1 = 0.f, p2 = 0.f;
#pragma unroll 8
    for (int d = seg * 64; d < seg * 64 + 64; ++d) {
        float w2 = wk[tt * 129 + d];
        p1 += tmp[d] * w2;
        p2 += sl[d] * w2;
    }
    prt[seg][tt] = p1;
    prt2[seg][tt] = p2;
    __syncthreads();
    if (t < 128) {
        float tdot = prt[0][t] + prt[1][t];
        float kdot = prt2[0][t] + prt2[1][t];
        float qs = 0.f;
#pragma unroll 8
        for (int d = 0; d < 128; ++d) qs += wqr[d] * sl[d];
        float bqa = bq[a];
        float sc = (tdot + qs * bkl[t] + bqa * kdot + Bn * bqa * bkl[t]) *
                   0.0883883476483184406f;
        scl[t] = sc;
    }
    __syncthreads();
    if (t < 128) {
        float mx = -1e30f;
        for (int i2 = 0; i2 < 128; ++i2) mx = fmaxf(mx, scl[i2]);
        scl2[t] = expf(scl[t] - mx);
    }
    __syncthreads();
    if (t < 128) {
        float sum = 0.f;
        for (int i2 = 0; i2 < 128; ++i2) sum += scl2[i2];
        wrow[t] = scl2[t] / sum;
    }
    __syncthreads();

    // M[a][t] = sum_c W[a,c] * Wv[c,t]  split over segments
    float pm = 0.f;
#pragma unroll 8
    for (int cc = seg * 64; cc < seg * 64 + 64; ++cc)
        pm += wrow[cc] * Wv[cc * 128 + tt];
    prt[seg][tt] = pm;
    __syncthreads();
    if (t < 128) {
        M16[a * 128 + t] = f2bf(prt[0][t] + prt[1][t]);
        float wo = Wo[a * 128 + t];
        Wo16[a * 128 + t] = f2bf(wo);
        scl[t] = wrow[t] * bvl[t];
        scl2[t] = wo;
    }
    __syncthreads();
    if (t < 64) { scl[t] += scl[t + 64]; scl2[t] += scl2[t + 64]; }
    __syncthreads();
    if (t == 0) {
        float cv = 0.f, wsm = 0.f;
        for (int cc = 0; cc < 64; ++cc) { cv += scl[cc]; wsm += scl2[cc]; }
        cvec[a] = cv; wsum[a] = wsm;
    }
}

// ---------------- pass 2 (bf16 input): per-group double GEMM -> output rows
__global__ __launch_bounds__(256, 2) void k_out16(const unsigned short* __restrict__ x16,
                                                  const unsigned short* __restrict__ M16,
                                                  const unsigned short* __restrict__ Wo16,
                                                  const float* __restrict__ cvec,
                                                  const float* __restrict__ wsum,
                                                  const float* __restrict__ bo,
                                                  float* __restrict__ out, int ngrp) {
    __shared__ short xsk[16384];  // pre-swizzled X_p bf16; reused as U^T
    __shared__ float csl[128], wsl[128], bol[128];
    int t = threadIdx.x;
    int l = t & 63, w = t >> 6, hi = l >> 4, c = l & 15;
    int p = blockIdx.x;

    // stage pre-swizzled bf16 tile: 8 x 16B per thread (L3-resident source)
    const s16x8* xg = (const s16x8*)(x16 + (size_t)p * 16384);
    s16x8 stg[8];
#pragma unroll
    for (int kk = 0; kk < 8; ++kk) stg[kk] = xg[kk * 256 + t];

    // M fragments; wave w owns r/o-tiles {2w, 2w+1}
    s16x8 bfM[2][4];
#pragma unroll
    for (int rt = 0; rt < 2; ++rt) {
        int r = (2 * w + rt) * 16 + c;
#pragma unroll
        for (int ks = 0; ks < 4; ++ks)
            bfM[rt][ks] = *(const s16x8*)&M16[r * 128 + ks * 32 + hi * 8];
    }
    if (t < 128) { csl[t] = cvec[t]; wsl[t] = wsum[t]; bol[t] = bo[t]; }

#pragma unroll
    for (int kk = 0; kk < 8; ++kk)
        *(s16x8*)&xsk[(kk * 256 + t) * 8] = stg[kk];
    __syncthreads();

    // GEMM1: U[j][r] = sum_d X[j,d] M[r,d]
    f32x4 acc[8][2] = {};
#pragma unroll
    for (int jt = 0; jt < 8; ++jt) {
        int j = jt * 16 + c;
        s16x8 af[4];
#pragma unroll
        for (int ks = 0; ks < 4; ++ks)
            af[ks] = *(const s16x8*)&xsk[j * 128 + ((ks * 32 + hi * 8) ^ ((j & 7) << 3))];
#pragma unroll
        for (int rt = 0; rt < 2; ++rt)
#pragma unroll
            for (int ks = 0; ks < 4; ++ks)
                acc[jt][rt] = __builtin_amdgcn_mfma_f32_16x16x32_bf16(af[ks], bfM[rt][ks], acc[jt][rt], 0, 0, 0);
    }
    __syncthreads();  // all waves done reading X tile

    // write U^T into the same buffer
#pragma unroll
    for (int jt = 0; jt < 8; ++jt)
#pragma unroll
        for (int rt = 0; rt < 2; ++rt) {
            int r = (2 * w + rt) * 16 + c;
            int j0 = jt * 16 + hi * 4;
            uint64_t pk = 0;
#pragma unroll
            for (int e = 0; e < 4; ++e) pk |= (uint64_t)f2bf(acc[jt][rt][e]) << (16 * e);
            *(uint64_t*)&xsk[r * 128 + (j0 ^ ((r & 7) << 3))] = pk;
        }
    __syncthreads();

    // Wo fragments loaded late
    s16x8 bfO[2][4];
#pragma unroll
    for (int ot = 0; ot < 2; ++ot) {
        int o = (2 * w + ot) * 16 + c;
#pragma unroll
        for (int ks = 0; ks < 4; ++ks)
            bfO[ot][ks] = *(const s16x8*)&Wo16[o * 128 + ks * 32 + hi * 8];
    }

    // GEMM2: Out[r][o] = sum_j U^T[r,j] Wo[o,j]
    f32x4 acc2[8][2] = {};
#pragma unroll
    for (int rt8 = 0; rt8 < 8; ++rt8) {
        int rr = rt8 * 16 + c;
        s16x8 af[4];
#pragma unroll
        for (int ks = 0; ks < 4; ++ks)
            af[ks] = *(const s16x8*)&xsk[rr * 128 + ((ks * 32 + hi * 8) ^ ((rr & 7) << 3))];
#pragma unroll
        for (int ot = 0; ot < 2; ++ot)
#pragma unroll
            for (int ks = 0; ks < 4; ++ks)
                acc2[rt8][ot] = __builtin_amdgcn_mfma_f32_16x16x32_bf16(af[ks], bfO[ot][ks], acc2[rt8][ot], 0, 0, 0);
    }

    // epilogue
#pragma unroll
    for (int rt8 = 0; rt8 < 8; ++rt8)
#pragma unroll
        for (int ot = 0; ot < 2; ++ot)
#pragma unroll
            for (int e = 0; e < 4; ++e) {
                int r = rt8 * 16 + hi * 4 + e;
                int o = (2 * w + ot) * 16 + c;
                float val = acc2[rt8][ot][e] + csl[r] * wsl[o] + bol[o];
                out[((long)r * ngrp + p) * 128 + o] = val;
            }
}

// ---------------- pass 2 (f32 fallback, r3-style) if workspace too small
__global__ __launch_bounds__(256, 2) void k_out32(const float* __restrict__ x,
                                                  const unsigned short* __restrict__ M16,
                                                  const unsigned short* __restrict__ Wo16,
                                                  const float* __restrict__ cvec,
                                                  const float* __restrict__ wsum,
                                                  const float* __restrict__ bo,
                                                  float* __restrict__ out, int ngrp) {
    __shared__ short xsk[16384];
    __shared__ float csl[128], wsl[128], bol[128];
    int t = threadIdx.x;
    int l = t & 63, w = t >> 6, hi = l >> 4, c = l & 15;
    int p = blockIdx.x;

    s16x8 bfM[2][4];
#pragma unroll
    for (int rt = 0; rt < 2; ++rt) {
        int r = (2 * w + rt) * 16 + c;
#pragma unroll
        for (int ks = 0; ks < 4; ++ks)
            bfM[rt][ks] = *(const s16x8*)&M16[r * 128 + ks * 32 + hi * 8];
    }
    if (t < 128) { csl[t] = cvec[t]; wsl[t] = wsum[t]; bol[t] = bo[t]; }

    const fvec4* xg = (const fvec4*)x;
    long xbase = (long)p * 4096;
#pragma unroll 4
    for (int kk = 0; kk < 16; ++kk) {
        int ft = kk * 256 + t;
        fvec4 v = xg[xbase + ft];
        int j = ft >> 5, d0 = (ft & 31) * 4;
        uint64_t pk = 0;
#pragma unroll
        for (int e = 0; e < 4; ++e) pk |= (uint64_t)f2bf(v[e]) << (16 * e);
        *(uint64_t*)&xsk[j * 128 + (d0 ^ ((j & 7) << 3))] = pk;
    }
    __syncthreads();

    f32x4 acc[8][2] = {};
#pragma unroll
    for (int jt = 0; jt < 8; ++jt) {
        int j = jt * 16 + c;
        s16x8 af[4];
#pragma unroll
        for (int ks = 0; ks < 4; ++ks)
            af[ks] = *(const s16x8*)&xsk[j * 128 + ((ks * 32 + hi * 8) ^ ((j & 7) << 3))];
#pragma unroll
        for (int rt = 0; rt < 2; ++rt)
#pragma unroll
            for (int ks = 0; ks < 4; ++ks)
                acc[jt][rt] = __builtin_amdgcn_mfma_f32_16x16x32_bf16(af[ks], bfM[rt][ks], acc[jt][rt], 0, 0, 0);
    }
    __syncthreads();

#pragma unroll
    for (int jt = 0; jt < 8; ++jt)
#pragma unroll
        for (int rt = 0; rt < 2; ++rt) {
            int r = (2 * w + rt) * 16 + c;
            int j0 = jt * 16 + hi * 4;
            uint64_t pk = 0;
#pragma unroll
            for (int e = 0; e < 4; ++e) pk |= (uint64_t)f2bf(acc[jt][rt][e]) << (16 * e);
            *(uint64_t*)&xsk[r * 128 + (j0 ^ ((r & 7) << 3))] = pk;
        }
    __syncthreads();

    s16x8 bfO[2][4];
#pragma unroll
    for (int ot = 0; ot < 2; ++ot) {
        int o = (2 * w + ot) * 16 + c;
#pragma unroll
        for (int ks = 0; ks < 4; ++ks)
            bfO[ot][ks] = *(const s16x8*)&Wo16[o * 128 + ks * 32 + hi * 8];
    }

    f32x4 acc2[8][2] = {};
#pragma unroll
    for (int rt8 = 0; rt8 < 8; ++rt8) {
        int rr = rt8 * 16 + c;
        s16x8 af[4];
#pragma unroll
        for (int ks = 0; ks < 4; ++ks)
            af[ks] = *(const s16x8*)&xsk[rr * 128 + ((ks * 32 + hi * 8) ^ ((rr & 7) << 3))];
#pragma unroll
        for (int ot = 0; ot < 2; ++ot)
#pragma unroll
            for (int ks = 0; ks < 4; ++ks)
                acc2[rt8][ot] = __builtin_amdgcn_mfma_f32_16x16x32_bf16(af[ks], bfO[ot][ks], acc2[rt8][ot], 0, 0, 0);
    }

#pragma unroll
    for (int rt8 = 0; rt8 < 8; ++rt8)
#pragma unroll
        for (int ot = 0; ot < 2; ++ot)
#pragma unroll
            for (int e = 0; e < 4; ++e) {
                int r = rt8 * 16 + hi * 4 + e;
                int o = (2 * w + ot) * 16 + c;
                float val = acc2[rt8][ot][e] + csl[r] * wsl[o] + bol[o];
                out[((long)r * ngrp + p) * 128 + o] = val;
            }
}

// ------------------------------------------------------------------- launcher
extern "C" void kernel_launch(void* const* d_in, const int* in_sizes, int n_in,
                              void* d_out, int out_size, void* d_ws, size_t ws_size,
                              hipStream_t stream) {
    const float* x  = (const float*)d_in[0];
    const float* Wq = (const float*)d_in[1];
    const float* bq = (const float*)d_in[2];
    const float* Wk = (const float*)d_in[3];
    const float* bk = (const float*)d_in[4];
    const float* Wv = (const float*)d_in[5];
    const float* bv = (const float*)d_in[6];
    const float* Wo = (const float*)d_in[7];
    const float* bo = (const float*)d_in[8];
    float* out = (float*)d_out;
    float* ws = (float*)d_ws;

    int Bn  = in_sizes[0] / DD;      // 262144
    int nb1 = Bn / ROWS_PER_BLK;     // 512
    int ngrp = Bn / DD;              // 2048

    float* parts = ws;
    float* G     = ws + (size_t)nb1 * PART_STRIDE;
    float* svec  = G + 16384;
    float* cvec  = svec + 128;
    float* wsumv = cvec + 128;
    unsigned short* M16  = (unsigned short*)(wsumv + 128);
    unsigned short* Wo16 = M16 + 16384;
    unsigned short* x16  = Wo16 + 16384;
    size_t needed = (size_t)((char*)(x16 + (size_t)Bn * DD) - (char*)ws);
    bool use16 = ws_size >= needed;

    hipLaunchKernelGGL(k_gram, dim3(nb1), dim3(512), 0, stream,
                       x, ws, use16 ? x16 : (unsigned short*)nullptr);
    hipLaunchKernelGGL(k_reduce, dim3(513), dim3(256), 0, stream,
                       ws, G, svec, nb1);
    hipLaunchKernelGGL(k_mid, dim3(128), dim3(256), 0, stream,
                       G, svec, Wq, bq, Wk, bk, Wv, bv, Wo,
                       M16, Wo16, cvec, wsumv, (float)Bn);
    if (use16)
        hipLaunchKernelGGL(k_out16, dim3(ngrp), dim3(256), 0, stream,
                           x16, M16, Wo16, cvec, wsumv, bo, out, ngrp);
    else
        hipLaunchKernelGGL(k_out32, dim3(ngrp), dim3(256), 0, stream,
                           x, M16, Wo16, cvec, wsumv, bo, out, ngrp);
}

// Round 8
// 135.838 us; speedup vs baseline: 1.0345x; 1.0345x over previous
//
#include <hip/hip_runtime.h>
#include <stdint.h>

// DenseAttention_61598420959334 — round 8:
//   k_gram rebuilt around ds_read_b64_tr_b16 (HW transpose read):
//     - CVT writes hi/lo bf16 planes directly in tr-read subtiled layout
//     - GRAM reads x^T fragments via tr-reads (no identity-MFMA transpose)
//     - ONE barrier per 32-row tile (was 3); LDS 41 KB (was 64)
//   x16 dump is now plain row-major; k_out16 swizzles at stage time.
//   k_reduce / k_mid / k_out32 unchanged from r7.

#define DD 128
#define ROWS_PER_BLK 512
#define KSTEPS 16
#define PART_STRIDE 16512  // 16384 G-partial + 128 s-partial

// tr-read LDS layout constants (shorts): x[j][a], j=8g+4r+e, a=16*ab+ac
//   offset = 648*ab + 320*r + 64*g + 16*e + ac   (ab-stride 648 => ~2-way banks)
#define AB_STRIDE 648
#define R_STRIDE  320
#define PLANE_SH  5184            // shorts per plane (8*648)
#define PLANE_B   10368           // bytes per plane
#define BUF_B     20736           // bytes per buffer (2 planes)

typedef float f32x4 __attribute__((ext_vector_type(4)));
typedef short s16x8 __attribute__((ext_vector_type(8)));
typedef float fvec4 __attribute__((ext_vector_type(4)));

__device__ __forceinline__ unsigned short f2bf(float f) {
    union { float f; uint32_t u; } v; v.f = f;
    uint32_t u = v.u;
    u += 0x7FFFu + ((u >> 16) & 1u);
    return (unsigned short)(u >> 16);
}
__device__ __forceinline__ float bf2f(unsigned short h) {
    union { uint32_t u; float f; } v; v.u = ((uint32_t)h) << 16;
    return v.f;
}
__device__ __forceinline__ s16x8 mk8(uint64_t lo, uint64_t hi) {
    union { uint64_t u[2]; s16x8 v; } x; x.u[0] = lo; x.u[1] = hi; return x.v;
}

// ---------------------------------------------------------------- pass 1: Gram
__global__ __launch_bounds__(512, 2) void k_gram(const float* __restrict__ x,
                                                 float* __restrict__ ws,
                                                 unsigned short* __restrict__ x16) {
    __shared__ __align__(16) short lds[2][2][PLANE_SH];  // [buf][hi/lo][subtiled]

    const int tid = threadIdx.x;
    const int l = tid & 63, w = tid >> 6;
    const int hi = l >> 4, c = l & 15;
    const int wr = w >> 1, wc = w & 1;
    const long rowbase = (long)blockIdx.x * ROWS_PER_BLK;
    const fvec4* xg = (const fvec4*)x;

    s16x8 ones;
#pragma unroll
    for (int i = 0; i < 8; ++i) ones[i] = (short)0x3F80;

    f32x4 acc[2][4] = {};
    f32x4 accs = {};

    // per-lane tr-read base addresses (byte offsets into LDS)
    const unsigned lbase = (unsigned)(uintptr_t)&lds[0][0][0];
    const unsigned vA = lbase + 2592u * (unsigned)wr + 8u * (unsigned)l;  // 1296*(2wr)
    const unsigned vB = lbase + 5184u * (unsigned)wc + 8u * (unsigned)l;  // 1296*(4wc)

    fvec4 rA0, rA1, rB0, rB1;

#define LOADS(kt, r0, r1) do {                                  \
        long _b = (rowbase + (long)(kt) * 32) * 32;             \
        r0 = xg[_b + tid]; r1 = xg[_b + 512 + tid];             \
    } while (0)

    // convert to hi/lo bf16, write both planes in tr-subtiled layout, dump hi
#define CVTWRITE(BUF, kt, r0, r1) do {                                          \
        _Pragma("unroll")                                                       \
        for (int _q = 0; _q < 2; ++_q) {                                        \
            fvec4 _v = _q ? r1 : r0;                                            \
            int _ft = tid + _q * 512;                                           \
            int _j = _ft >> 5, _d0 = (_ft & 31) * 4;                            \
            uint64_t _ph = 0, _pl = 0;                                          \
            _Pragma("unroll")                                                   \
            for (int _e = 0; _e < 4; ++_e) {                                    \
                float _f = _v[_e];                                              \
                unsigned short _hb = f2bf(_f);                                  \
                unsigned short _lb = f2bf(_f - bf2f(_hb));                      \
                _ph |= (uint64_t)_hb << (16 * _e);                              \
                _pl |= (uint64_t)_lb << (16 * _e);                              \
            }                                                                   \
            int _off = AB_STRIDE * (_d0 >> 4) + R_STRIDE * ((_j >> 2) & 1) +    \
                       64 * (_j >> 3) + 16 * (_j & 3) + (_d0 & 15);             \
            *(uint64_t*)&lds[BUF][0][_off] = _ph;                               \
            *(uint64_t*)&lds[BUF][1][_off] = _pl;                               \
            if (x16)                                                            \
                *(uint64_t*)&x16[(rowbase + (long)(kt) * 32 + _j) * 128 + _d0] = _ph; \
        }                                                                       \
    } while (0)

    // Gram update from tile in buf BUF via tr-reads
#define GRAM(BUF) do {                                                          \
        uint64_t fa[2][2][2]; /* [mi][plane][r] */                              \
        uint64_t fb[4][2][2]; /* [ni][plane][r] */                              \
        _Pragma("unroll")                                                       \
        for (int _mi = 0; _mi < 2; ++_mi)                                       \
            _Pragma("unroll")                                                   \
            for (int _hl = 0; _hl < 2; ++_hl)                                   \
                _Pragma("unroll")                                               \
                for (int _r = 0; _r < 2; ++_r) {                                \
                    unsigned _ad = vA + (unsigned)((BUF) * BUF_B +              \
                        _hl * PLANE_B + _mi * 1296 + _r * 640);                 \
                    asm volatile("ds_read_b64_tr_b16 %0, %1"                    \
                                 : "=v"(fa[_mi][_hl][_r]) : "v"(_ad));          \
                }                                                               \
        _Pragma("unroll")                                                       \
        for (int _ni = 0; _ni < 4; ++_ni)                                       \
            _Pragma("unroll")                                                   \
            for (int _hl = 0; _hl < 2; ++_hl)                                   \
                _Pragma("unroll")                                               \
                for (int _r = 0; _r < 2; ++_r) {                                \
                    unsigned _ad = vB + (unsigned)((BUF) * BUF_B +              \
                        _hl * PLANE_B + _ni * 1296 + _r * 640);                 \
                    asm volatile("ds_read_b64_tr_b16 %0, %1"                    \
                                 : "=v"(fb[_ni][_hl][_r]) : "v"(_ad));          \
                }                                                               \
        asm volatile("s_waitcnt lgkmcnt(0)" ::: "memory");                      \
        __builtin_amdgcn_sched_barrier(0);                                      \
        s16x8 Ah[2], Al[2];                                                     \
        _Pragma("unroll")                                                       \
        for (int _mi = 0; _mi < 2; ++_mi) {                                     \
            Ah[_mi] = mk8(fa[_mi][0][0], fa[_mi][0][1]);                        \
            Al[_mi] = mk8(fa[_mi][1][0], fa[_mi][1][1]);                        \
        }                                                                       \
        _Pragma("unroll")                                                       \
        for (int _ni = 0; _ni < 4; ++_ni) {                                     \
            s16x8 Bh = mk8(fb[_ni][0][0], fb[_ni][0][1]);                       \
            s16x8 Bl = mk8(fb[_ni][1][0], fb[_ni][1][1]);                       \
            _Pragma("unroll")                                                   \
            for (int _mi = 0; _mi < 2; ++_mi) {                                 \
                acc[_mi][_ni] = __builtin_amdgcn_mfma_f32_16x16x32_bf16(Ah[_mi], Bh, acc[_mi][_ni], 0, 0, 0); \
                acc[_mi][_ni] = __builtin_amdgcn_mfma_f32_16x16x32_bf16(Ah[_mi], Bl, acc[_mi][_ni], 0, 0, 0); \
                acc[_mi][_ni] = __builtin_amdgcn_mfma_f32_16x16x32_bf16(Al[_mi], Bh, acc[_mi][_ni], 0, 0, 0); \
            }                                                                   \
            if (_ni == wr) {                                                    \
                accs = __builtin_amdgcn_mfma_f32_16x16x32_bf16(ones, Bh, accs, 0, 0, 0); \
                accs = __builtin_amdgcn_mfma_f32_16x16x32_bf16(ones, Bl, accs, 0, 0, 0); \
            }                                                                   \
        }                                                                       \
    } while (0)

    // prologue: tile0 -> buf0, tile1 -> regs
    LOADS(0, rA0, rA1);
    CVTWRITE(0, 0, rA0, rA1);
    LOADS(1, rB0, rB1);
    __syncthreads();

#pragma unroll 1
    for (int kt = 0; kt < KSTEPS; kt += 2) {
        if (kt + 2 < KSTEPS) LOADS(kt + 2, rA0, rA1);
        CVTWRITE(1, kt + 1, rB0, rB1);   // write tile kt+1 while computing kt
        GRAM(0);
        __syncthreads();
        if (kt + 3 < KSTEPS) LOADS(kt + 3, rB0, rB1);
        if (kt + 2 < KSTEPS) CVTWRITE(0, kt + 2, rA0, rA1);
        GRAM(1);
        __syncthreads();
    }

    long pbase = (long)blockIdx.x * PART_STRIDE;
#pragma unroll
    for (int mi = 0; mi < 2; ++mi)
#pragma unroll
        for (int ni = 0; ni < 4; ++ni)
#pragma unroll
            for (int e = 0; e < 4; ++e) {
                int a = (wr * 2 + mi) * 16 + hi * 4 + e;
                int b = (wc * 4 + ni) * 16 + c;
                ws[pbase + a * 128 + b] = acc[mi][ni][e];
            }
    if (hi == 0) {
        int nbs = wc * 4 + wr;
        ws[pbase + 16384 + nbs * 16 + c] = accs[0];
    }
#undef LOADS
#undef CVTWRITE
#undef GRAM
}

// ------------------------------------------------------- reduce partials -> G, s
__global__ __launch_bounds__(256) void k_reduce(const float* __restrict__ parts,
                                                float* __restrict__ g_out,
                                                float* __restrict__ s_out, int nb1) {
    __shared__ float red[256];
    int b = blockIdx.x, t = threadIdx.x;
    if (b < 512) {
        int d1 = b >> 2, q = b & 3;
        int c32 = t & 31, pg = t >> 5;
        int per = nb1 >> 3;
        int e = d1 * 128 + q * 32 + c32;
        float acc = 0.f;
#pragma unroll 4
        for (int p = pg * per; p < (pg + 1) * per; ++p)
            acc += parts[(long)p * PART_STRIDE + e];
        red[t] = acc;
        __syncthreads();
        if (pg == 0) {
            float s = red[c32];
#pragma unroll
            for (int k = 1; k < 8; ++k) s += red[k * 32 + c32];
            g_out[e] = s;
        }
    } else {
        int ee = t & 127, hg = t >> 7;
        int per = nb1 >> 1;
        float acc = 0.f;
#pragma unroll 4
        for (int p = hg * per; p < (hg + 1) * per; ++p)
            acc += parts[(long)p * PART_STRIDE + 16384 + ee];
        red[t] = acc;
        __syncthreads();
        if (hg == 0) s_out[ee] = red[ee] + red[128 + ee];
    }
}

// ---- k_mid: scores row a from G (in LDS) + softmax + M row + c/wsum + casts
__global__ __launch_bounds__(256) void k_mid(const float* __restrict__ G,
                                             const float* __restrict__ s,
                                             const float* __restrict__ Wq,
                                             const float* __restrict__ bq,
                                             const float* __restrict__ Wk,
                                             const float* __restrict__ bk,
                                             const float* __restrict__ Wv,
                                             const float* __restrict__ bv,
                                             const float* __restrict__ Wo,
                                             unsigned short* __restrict__ M16,
                                             unsigned short* __restrict__ Wo16,
                                             float* __restrict__ cvec,
                                             float* __restrict__ wsum, float Bn) {
    __shared__ float gl[16384];      // G row-major
    __shared__ float wk[128 * 129];  // Wk padded (conflict-free row reads)
    __shared__ float wqr[128], sl[128], bkl[128], bvl[128];
    __shared__ float prt[2][128], prt2[2][128];
    __shared__ float tmp[128], scl[128], wrow[128], scl2[128];
    int t = threadIdx.x, a = blockIdx.x;
    int tt = t & 127, seg = t >> 7;

    {
        const fvec4* gg = (const fvec4*)G;
        fvec4* gs = (fvec4*)gl;
        for (int i = t; i < 4096; i += 256) gs[i] = gg[i];
    }
    for (int idx = t; idx < 16384; idx += 256) {
        int r = idx >> 7, cc = idx & 127;
        wk[r * 129 + cc] = Wk[idx];
    }
    if (t < 128) {
        wqr[t] = Wq[a * 128 + t];
        sl[t] = s[t]; bkl[t] = bk[t]; bvl[t] = bv[t];
    }
    __syncthreads();

    float tm = 0.f;
#pragma unroll 8
    for (int d1 = seg * 64; d1 < seg * 64 + 64; ++d1) tm += wqr[d1] * gl[d1 * 128 + tt];
    prt[seg][tt] = tm;
    __syncthreads();
    if (t < 128) tmp[t] = prt[0][t] + prt[1][t];
    __syncthreads();

    float p1 = 0.f, p2 = 0.f;
#pragma unroll 8
    for (int d = seg * 64; d < seg * 64 + 64; ++d) {
        float w2 = wk[tt * 129 + d];
        p1 += tmp[d] * w2;
        p2 += sl[d] * w2;
    }
    prt[seg][tt] = p1;
    prt2[seg][tt] = p2;
    __syncthreads();
    if (t < 128) {
        float tdot = prt[0][t] + prt[1][t];
        float kdot = prt2[0][t] + prt2[1][t];
        float qs = 0.f;
#pragma unroll 8
        for (int d = 0; d < 128; ++d) qs += wqr[d] * sl[d];
        float bqa = bq[a];
        float sc = (tdot + qs * bkl[t] + bqa * kdot + Bn * bqa * bkl[t]) *
                   0.0883883476483184406f;
        scl[t] = sc;
    }
    __syncthreads();
    if (t < 128) {
        float mx = -1e30f;
        for (int i2 = 0; i2 < 128; ++i2) mx = fmaxf(mx, scl[i2]);
        scl2[t] = expf(scl[t] - mx);
    }
    __syncthreads();
    if (t < 128) {
        float sum = 0.f;
        for (int i2 = 0; i2 < 128; ++i2) sum += scl2[i2];
        wrow[t] = scl2[t] / sum;
    }
    __syncthreads();

    float pm = 0.f;
#pragma unroll 8
    for (int cc = seg * 64; cc < seg * 64 + 64; ++cc)
        pm += wrow[cc] * Wv[cc * 128 + tt];
    prt[seg][tt] = pm;
    __syncthreads();
    if (t < 128) {
        M16[a * 128 + t] = f2bf(prt[0][t] + prt[1][t]);
        float wo = Wo[a * 128 + t];
        Wo16[a * 128 + t] = f2bf(wo);
        scl[t] = wrow[t] * bvl[t];
        scl2[t] = wo;
    }
    __syncthreads();
    if (t < 64) { scl[t] += scl[t + 64]; scl2[t] += scl2[t + 64]; }
    __syncthreads();
    if (t == 0) {
        float cv = 0.f, wsm = 0.f;
        for (int cc = 0; cc < 64; ++cc) { cv += scl[cc]; wsm += scl2[cc]; }
        cvec[a] = cv; wsum[a] = wsm;
    }
}

// ---------------- pass 2 (bf16 input): per-group double GEMM -> output rows
__global__ __launch_bounds__(256, 2) void k_out16(const unsigned short* __restrict__ x16,
                                                  const unsigned short* __restrict__ M16,
                                                  const unsigned short* __restrict__ Wo16,
                                                  const float* __restrict__ cvec,
                                                  const float* __restrict__ wsum,
                                                  const float* __restrict__ bo,
                                                  float* __restrict__ out, int ngrp) {
    __shared__ short xsk[16384];  // X_p bf16 (XOR-swizzled); reused as U^T
    __shared__ float csl[128], wsl[128], bol[128];
    int t = threadIdx.x;
    int l = t & 63, w = t >> 6, hi = l >> 4, c = l & 15;
    int p = blockIdx.x;

    // stage row-major bf16 tile, swizzling on LDS write
    const s16x8* xg = (const s16x8*)(x16 + (size_t)p * 16384);
    s16x8 stg[8];
#pragma unroll
    for (int kk = 0; kk < 8; ++kk) stg[kk] = xg[kk * 256 + t];

    s16x8 bfM[2][4];
#pragma unroll
    for (int rt = 0; rt < 2; ++rt) {
        int r = (2 * w + rt) * 16 + c;
#pragma unroll
        for (int ks = 0; ks < 4; ++ks)
            bfM[rt][ks] = *(const s16x8*)&M16[r * 128 + ks * 32 + hi * 8];
    }
    if (t < 128) { csl[t] = cvec[t]; wsl[t] = wsum[t]; bol[t] = bo[t]; }

#pragma unroll
    for (int kk = 0; kk < 8; ++kk) {
        int ft = kk * 256 + t;
        int j = ft >> 4, d08 = (ft & 15) * 8;
        *(s16x8*)&xsk[j * 128 + (d08 ^ ((j & 7) << 3))] = stg[kk];
    }
    __syncthreads();

    // GEMM1: U[j][r] = sum_d X[j,d] M[r,d]
    f32x4 acc[8][2] = {};
#pragma unroll
    for (int jt = 0; jt < 8; ++jt) {
        int j = jt * 16 + c;
        s16x8 af[4];
#pragma unroll
        for (int ks = 0; ks < 4; ++ks)
            af[ks] = *(const s16x8*)&xsk[j * 128 + ((ks * 32 + hi * 8) ^ ((j & 7) << 3))];
#pragma unroll
        for (int rt = 0; rt < 2; ++rt)
#pragma unroll
            for (int ks = 0; ks < 4; ++ks)
                acc[jt][rt] = __builtin_amdgcn_mfma_f32_16x16x32_bf16(af[ks], bfM[rt][ks], acc[jt][rt], 0, 0, 0);
    }
    __syncthreads();

    // write U^T into the same buffer
#pragma unroll
    for (int jt = 0; jt < 8; ++jt)
#pragma unroll
        for (int rt = 0; rt < 2; ++rt) {
            int r = (2 * w + rt) * 16 + c;
            int j0 = jt * 16 + hi * 4;
            uint64_t pk = 0;
#pragma unroll
            for (int e = 0; e < 4; ++e) pk |= (uint64_t)f2bf(acc[jt][rt][e]) << (16 * e);
            *(uint64_t*)&xsk[r * 128 + (j0 ^ ((r & 7) << 3))] = pk;
        }
    __syncthreads();

    s16x8 bfO[2][4];
#pragma unroll
    for (int ot = 0; ot < 2; ++ot) {
        int o = (2 * w + ot) * 16 + c;
#pragma unroll
        for (int ks = 0; ks < 4; ++ks)
            bfO[ot][ks] = *(const s16x8*)&Wo16[o * 128 + ks * 32 + hi * 8];
    }

    // GEMM2: Out[r][o] = sum_j U^T[r,j] Wo[o,j]
    f32x4 acc2[8][2] = {};
#pragma unroll
    for (int rt8 = 0; rt8 < 8; ++rt8) {
        int rr = rt8 * 16 + c;
        s16x8 af[4];
#pragma unroll
        for (int ks = 0; ks < 4; ++ks)
            af[ks] = *(const s16x8*)&xsk[rr * 128 + ((ks * 32 + hi * 8) ^ ((rr & 7) << 3))];
#pragma unroll
        for (int ot = 0; ot < 2; ++ot)
#pragma unroll
            for (int ks = 0; ks < 4; ++ks)
                acc2[rt8][ot] = __builtin_amdgcn_mfma_f32_16x16x32_bf16(af[ks], bfO[ot][ks], acc2[rt8][ot], 0, 0, 0);
    }

#pragma unroll
    for (int rt8 = 0; rt8 < 8; ++rt8)
#pragma unroll
        for (int ot = 0; ot < 2; ++ot)
#pragma unroll
            for (int e = 0; e < 4; ++e) {
                int r = rt8 * 16 + hi * 4 + e;
                int o = (2 * w + ot) * 16 + c;
                float val = acc2[rt8][ot][e] + csl[r] * wsl[o] + bol[o];
                out[((long)r * ngrp + p) * 128 + o] = val;
            }
}

// ---------------- pass 2 (f32 fallback, r3-style) if workspace too small
__global__ __launch_bounds__(256, 2) void k_out32(const float* __restrict__ x,
                                                  const unsigned short* __restrict__ M16,
                                                  const unsigned short* __restrict__ Wo16,
                                                  const float* __restrict__ cvec,
                                                  const float* __restrict__ wsum,
                                                  const float* __restrict__ bo,
                                                  float* __restrict__ out, int ngrp) {
    __shared__ short xsk[16384];
    __shared__ float csl[128], wsl[128], bol[128];
    int t = threadIdx.x;
    int l = t & 63, w = t >> 6, hi = l >> 4, c = l & 15;
    int p = blockIdx.x;

    s16x8 bfM[2][4];
#pragma unroll
    for (int rt = 0; rt < 2; ++rt) {
        int r = (2 * w + rt) * 16 + c;
#pragma unroll
        for (int ks = 0; ks < 4; ++ks)
            bfM[rt][ks] = *(const s16x8*)&M16[r * 128 + ks * 32 + hi * 8];
    }
    if (t < 128) { csl[t] = cvec[t]; wsl[t] = wsum[t]; bol[t] = bo[t]; }

    const fvec4* xg = (const fvec4*)x;
    long xbase = (long)p * 4096;
#pragma unroll 4
    for (int kk = 0; kk < 16; ++kk) {
        int ft = kk * 256 + t;
        fvec4 v = xg[xbase + ft];
        int j = ft >> 5, d0 = (ft & 31) * 4;
        uint64_t pk = 0;
#pragma unroll
        for (int e = 0; e < 4; ++e) pk |= (uint64_t)f2bf(v[e]) << (16 * e);
        *(uint64_t*)&xsk[j * 128 + (d0 ^ ((j & 7) << 3))] = pk;
    }
    __syncthreads();

    f32x4 acc[8][2] = {};
#pragma unroll
    for (int jt = 0; jt < 8; ++jt) {
        int j = jt * 16 + c;
        s16x8 af[4];
#pragma unroll
        for (int ks = 0; ks < 4; ++ks)
            af[ks] = *(const s16x8*)&xsk[j * 128 + ((ks * 32 + hi * 8) ^ ((j & 7) << 3))];
#pragma unroll
        for (int rt = 0; rt < 2; ++rt)
#pragma unroll
            for (int ks = 0; ks < 4; ++ks)
                acc[jt][rt] = __builtin_amdgcn_mfma_f32_16x16x32_bf16(af[ks], bfM[rt][ks], acc[jt][rt], 0, 0, 0);
    }
    __syncthreads();

#pragma unroll
    for (int jt = 0; jt < 8; ++jt)
#pragma unroll
        for (int rt = 0; rt < 2; ++rt) {
            int r = (2 * w + rt) * 16 + c;
            int j0 = jt * 16 + hi * 4;
            uint64_t pk = 0;
#pragma unroll
            for (int e = 0; e < 4; ++e) pk |= (uint64_t)f2bf(acc[jt][rt][e]) << (16 * e);
            *(uint64_t*)&xsk[r * 128 + (j0 ^ ((r & 7) << 3))] = pk;
        }
    __syncthreads();

    s16x8 bfO[2][4];
#pragma unroll
    for (int ot = 0; ot < 2; ++ot) {
        int o = (2 * w + ot) * 16 + c;
#pragma unroll
        for (int ks = 0; ks < 4; ++ks)
            bfO[ot][ks] = *(const s16x8*)&Wo16[o * 128 + ks * 32 + hi * 8];
    }

    f32x4 acc2[8][2] = {};
#pragma unroll
    for (int rt8 = 0; rt8 < 8; ++rt8) {
        int rr = rt8 * 16 + c;
        s16x8 af[4];
#pragma unroll
        for (int ks = 0; ks < 4; ++ks)
            af[ks] = *(const s16x8*)&xsk[rr * 128 + ((ks * 32 + hi * 8) ^ ((rr & 7) << 3))];
#pragma unroll
        for (int ot = 0; ot < 2; ++ot)
#pragma unroll
            for (int ks = 0; ks < 4; ++ks)
                acc2[rt8][ot] = __builtin_amdgcn_mfma_f32_16x16x32_bf16(af[ks], bfO[ot][ks], acc2[rt8][ot], 0, 0, 0);
    }

#pragma unroll
    for (int rt8 = 0; rt8 < 8; ++rt8)
#pragma unroll
        for (int ot = 0; ot < 2; ++ot)
#pragma unroll
            for (int e = 0; e < 4; ++e) {
                int r = rt8 * 16 + hi * 4 + e;
                int o = (2 * w + ot) * 16 + c;
                float val = acc2[rt8][ot][e] + csl[r] * wsl[o] + bol[o];
                out[((long)r * ngrp + p) * 128 + o] = val;
            }
}

// ------------------------------------------------------------------- launcher
extern "C" void kernel_launch(void* const* d_in, const int* in_sizes, int n_in,
                              void* d_out, int out_size, void* d_ws, size_t ws_size,
                              hipStream_t stream) {
    const float* x  = (const float*)d_in[0];
    const float* Wq = (const float*)d_in[1];
    const float* bq = (const float*)d_in[2];
    const float* Wk = (const float*)d_in[3];
    const float* bk = (const float*)d_in[4];
    const float* Wv = (const float*)d_in[5];
    const float* bv = (const float*)d_in[6];
    const float* Wo = (const float*)d_in[7];
    const float* bo = (const float*)d_in[8];
    float* out = (float*)d_out;
    float* ws = (float*)d_ws;

    int Bn  = in_sizes[0] / DD;      // 262144
    int nb1 = Bn / ROWS_PER_BLK;     // 512
    int ngrp = Bn / DD;              // 2048

    float* parts = ws;
    float* G     = ws + (size_t)nb1 * PART_STRIDE;
    float* svec  = G + 16384;
    float* cvec  = svec + 128;
    float* wsumv = cvec + 128;
    unsigned short* M16  = (unsigned short*)(wsumv + 128);
    unsigned short* Wo16 = M16 + 16384;
    unsigned short* x16  = Wo16 + 16384;
    size_t needed = (size_t)((char*)(x16 + (size_t)Bn * DD) - (char*)ws);
    bool use16 = ws_size >= needed;

    hipLaunchKernelGGL(k_gram, dim3(nb1), dim3(512), 0, stream,
                       x, ws, use16 ? x16 : (unsigned short*)nullptr);
    hipLaunchKernelGGL(k_reduce, dim3(513), dim3(256), 0, stream,
                       ws, G, svec, nb1);
    hipLaunchKernelGGL(k_mid, dim3(128), dim3(256), 0, stream,
                       G, svec, Wq, bq, Wk, bk, Wv, bv, Wo,
                       M16, Wo16, cvec, wsumv, (float)Bn);
    if (use16)
        hipLaunchKernelGGL(k_out16, dim3(ngrp), dim3(256), 0, stream,
                           x16, M16, Wo16, cvec, wsumv, bo, out, ngrp);
    else
        hipLaunchKernelGGL(k_out32, dim3(ngrp), dim3(256), 0, stream,
                           x, M16, Wo16, cvec, wsumv, bo, out, ngrp);
}